// Round 6
// baseline (159.683 us; speedup 1.0000x reference)
//
#include <hip/hip_runtime.h>
#include <math.h>

// SSIM loss, fp32, N=16 C=3 H=W=512, 11x11 Gaussian sigma=1.5, zero-padded,
// separable — both blur passes on the MFMA pipe (16x16x32 bf16).
// Round-6 restructure: 5 waves/block (one wave per 16-col V-chunk, balanced),
// each block processes NT=4 vertical 16-row tiles (64x64 px) with register
// double-buffer prefetch of the next tile's global loads. Barrier between
// V-writes and H-reads is raw s_barrier + lgkmcnt(0) only, so prefetch
// vmcnt stays outstanding across pass H (__syncthreads would drain vmcnt(0)).

#define IMG 512
#define TW 64
#define TH 16
#define NT 4                    // vertical tiles per block
#define GXD 8
#define GYD 8                   // 512 / (TH*NT)
#define GZD 48
#define NB (GXD * GYD * GZD)    // 3072
#define VBS 88                  // vb row stride in bf16 (16B-aligned)
#define C1c 0.0001f
#define C2c 0.0009f
#define NTOTAL 12582912.0f

typedef short bf16x8 __attribute__((ext_vector_type(8)));
typedef float f32x4 __attribute__((ext_vector_type(4)));

struct GaussB { unsigned short gb[11]; };   // bf16 weights (host-RNE)

// pack bf16(a) low 16, bf16(b) high 16 — one v_perm_b32 (truncation)
__device__ __forceinline__ unsigned int pkbf(float a, float b) {
    return __builtin_amdgcn_perm(__float_as_uint(b), __float_as_uint(a),
                                 0x07060302u);
}

// wait lgkmcnt(0) ONLY (vmcnt stays outstanding), then barrier
__device__ __forceinline__ void barrier_lds_only() {
    __builtin_amdgcn_s_waitcnt(0xc07f);
    __builtin_amdgcn_s_barrier();
}

// load 8 vertically-strided pixels of column gx starting at row gy0
__device__ __forceinline__ void load_col8(const float* __restrict__ pbase,
                                          const float* __restrict__ tbase,
                                          int gx, int gy0, bool xin,
                                          float* pv, float* tv)
{
    const bool ok = xin & (gy0 >= 0) & (gy0 <= IMG - 8);
    if (ok) {
        const float* pp = pbase + gy0 * IMG + gx;
        const float* tp = tbase + gy0 * IMG + gx;
        #pragma unroll
        for (int j = 0; j < 8; ++j) {
            pv[j] = pp[j * IMG];
            tv[j] = tp[j * IMG];
        }
    } else {
        #pragma unroll
        for (int j = 0; j < 8; ++j) {
            int gy = gy0 + j;
            bool in = xin && ((unsigned)gy < (unsigned)IMG);
            int idx = in ? (gy * IMG + gx) : 0;
            float a = pbase[idx];
            float b = tbase[idx];
            pv[j] = in ? a : 0.0f;
            tv[j] = in ? b : 0.0f;
        }
    }
}

template <bool USE_ATOMIC>
__global__ __launch_bounds__(320, 8) void ssim_main(
    const float* __restrict__ pred,
    const float* __restrict__ target,
    float* __restrict__ sink,
    GaussB gwb)
{
    __shared__ unsigned short Wmat[16][32];       // 1 KB
    __shared__ unsigned short vb[5][16][VBS];     // 14080 B
    __shared__ float red[5];

    const int tid  = threadIdx.x;
    const int w    = tid >> 6;        // wave 0..4 (= V-chunk id)
    const int lane = tid & 63;
    const int quad = lane >> 4;
    const int n16  = lane & 15;
    const int tx0  = blockIdx.x * TW;
    const int tyb  = blockIdx.y * (TH * NT);
    const float* __restrict__ pbase = pred   + (size_t)blockIdx.z * (IMG * IMG);
    const float* __restrict__ tbase = target + (size_t)blockIdx.z * (IMG * IMG);

    // ---- W: W[i][k] = g[k-i] for k-i in [0,10], else 0 ----
    for (int idx = tid; idx < 512; idx += 320) {
        int i = idx >> 5, k = idx & 31, d = k - i;
        Wmat[i][k] = (d >= 0 && d <= 10) ? gwb.gb[d] : 0;
    }
    __syncthreads();
    const bf16x8 wfrag = *(const bf16x8*)&Wmat[n16][quad * 8];

    const int gx  = tx0 - 5 + 16 * w + n16;   // this lane's input column
    const bool xin = (unsigned)gx < (unsigned)IMG;
    const int k0  = quad * 8;                 // lane's row offset in 32-window
    const int vcol = 16 * w + 4 * quad;
    const f32x4 z = {0.0f, 0.0f, 0.0f, 0.0f};

    float pv[2][8], tv[2][8];
    load_col8(pbase, tbase, gx, tyb - 5 + k0, xin, pv[0], tv[0]);

    float lsum = 0.0f;

    #pragma unroll
    for (int i = 0; i < NT; ++i) {
        const int cur = i & 1, nxt = cur ^ 1;
        // prefetch next tile's inputs (stays in flight across pass H)
        if (i + 1 < NT)
            load_col8(pbase, tbase, gx, tyb + TH * (i + 1) - 5 + k0, xin,
                      pv[nxt], tv[nxt]);

        // ---- Pass V: products -> bf16 frag -> MFMA -> vb (channel-serial) ----
        float ps[8], ts[8];
        #pragma unroll
        for (int j = 0; j < 8; ++j) {
            ps[j] = fmaf(pv[cur][j], 0.5f, 0.5f);
            ts[j] = fmaf(tv[cur][j], 0.5f, 0.5f);
        }
        #pragma unroll
        for (int ch = 0; ch < 5; ++ch) {
            union { bf16x8 v; unsigned int u[4]; } f;
            #pragma unroll
            for (int h = 0; h < 4; ++h) {
                float a0, a1;
                if      (ch == 0) { a0 = ps[2*h];            a1 = ps[2*h+1]; }
                else if (ch == 1) { a0 = ts[2*h];            a1 = ts[2*h+1]; }
                else if (ch == 2) { a0 = ps[2*h]*ps[2*h];    a1 = ps[2*h+1]*ps[2*h+1]; }
                else if (ch == 3) { a0 = ts[2*h]*ts[2*h];    a1 = ts[2*h+1]*ts[2*h+1]; }
                else              { a0 = ps[2*h]*ts[2*h];    a1 = ps[2*h+1]*ts[2*h+1]; }
                f.u[h] = pkbf(a0, a1);
            }
            f32x4 d = __builtin_amdgcn_mfma_f32_16x16x32_bf16(f.v, wfrag, z, 0, 0, 0);
            union { ushort4 s; unsigned int u[2]; } pk;
            pk.u[0] = pkbf(d[0], d[1]);
            pk.u[1] = pkbf(d[2], d[3]);
            *(ushort4*)&vb[ch][n16][vcol] = pk.s;
        }
        barrier_lds_only();   // V writes visible; prefetch vmcnt untouched

        // ---- Pass H: waves 0..3 -> output cols 16w..16w+15 ----
        if (w < 4) {
            f32x4 r[5];
            #pragma unroll
            for (int ch = 0; ch < 5; ++ch) {
                bf16x8 a = *(const bf16x8*)&vb[ch][n16][16 * w + 8 * quad];
                r[ch] = __builtin_amdgcn_mfma_f32_16x16x32_bf16(a, wfrag, z, 0, 0, 0);
            }
            #pragma unroll
            for (int j = 0; j < 4; ++j) {
                float mp = r[0][j], mt = r[1][j];
                float mp2 = mp * mp, mt2 = mt * mt, mpt = mp * mt;
                float sig_p  = r[2][j] - mp2;
                float sig_t  = r[3][j] - mt2;
                float sig_pt = r[4][j] - mpt;
                float num = (2.0f * mpt + C1c) * (2.0f * sig_pt + C2c);
                float den = (mp2 + mt2 + C1c) * (sig_p + sig_t + C2c);
                lsum = fmaf(num, __builtin_amdgcn_rcpf(den), lsum);
            }
        }
        __syncthreads();      // vb safe to overwrite next iteration
    }

    // ---- block reduction ----
    #pragma unroll
    for (int off = 32; off > 0; off >>= 1)
        lsum += __shfl_down(lsum, off, 64);
    if (lane == 0) red[w] = lsum;
    __syncthreads();
    if (tid == 0) {
        float s = red[0] + red[1] + red[2] + red[3];   // wave 4 contributes 0
        if (USE_ATOMIC) {
            atomicAdd(sink, s);
        } else {
            int bid = blockIdx.x + GXD * (blockIdx.y + GYD * blockIdx.z);
            sink[bid] = s;
        }
    }
}

__global__ __launch_bounds__(256) void ssim_reduce(const float* __restrict__ partials,
                                                   float* __restrict__ out)
{
    __shared__ float red[4];
    const int tid = threadIdx.x;
    float s = 0.0f;
    const float4* p4 = (const float4*)partials;
    #pragma unroll
    for (int j = 0; j < NB / 1024; ++j) {   // 3072/4 = 768 float4 / 256
        float4 v = p4[tid + 256 * j];
        s += v.x + v.y + v.z + v.w;
    }
    #pragma unroll
    for (int off = 32; off > 0; off >>= 1)
        s += __shfl_down(s, off, 64);
    if ((tid & 63) == 0) red[tid >> 6] = s;
    __syncthreads();
    if (tid == 0)
        out[0] = 1.0f - (red[0] + red[1] + red[2] + red[3]) / NTOTAL;
}

__global__ void ssim_zero(float* accum) { accum[0] = 0.0f; }
__global__ void ssim_final(const float* accum, float* out) {
    out[0] = 1.0f - accum[0] / NTOTAL;
}

extern "C" void kernel_launch(void* const* d_in, const int* in_sizes, int n_in,
                              void* d_out, int out_size, void* d_ws, size_t ws_size,
                              hipStream_t stream) {
    const float* pred   = (const float*)d_in[0];
    const float* target = (const float*)d_in[1];
    float* out = (float*)d_out;

    // Gaussian weights in double, RNE-rounded to bf16 on host
    GaussB gwb;
    double vals[11], s = 0.0;
    for (int i = 0; i < 11; ++i) {
        double d = (double)i - 5.0;
        vals[i] = exp(-(d * d) / (2.0 * 1.5 * 1.5));
        s += vals[i];
    }
    for (int i = 0; i < 11; ++i) {
        float f = (float)(vals[i] / s);
        unsigned int u;
        __builtin_memcpy(&u, &f, 4);
        unsigned int rounded = (u + 0x7FFFu + ((u >> 16) & 1u)) >> 16;  // RNE
        gwb.gb[i] = (unsigned short)rounded;
    }

    dim3 grid(GXD, GYD, GZD);   // 8 x 8 x 48 = 3072 blocks
    if (ws_size >= (size_t)NB * sizeof(float)) {
        float* partials = (float*)d_ws;
        ssim_main<false><<<grid, 320, 0, stream>>>(pred, target, partials, gwb);
        ssim_reduce<<<1, 256, 0, stream>>>(partials, out);
    } else {
        float* accum = (float*)d_ws;
        ssim_zero<<<1, 1, 0, stream>>>(accum);
        ssim_main<true><<<grid, 320, 0, stream>>>(pred, target, accum, gwb);
        ssim_final<<<1, 1, 0, stream>>>(accum, out);
    }
}

// Round 7
// 140.726 us; speedup vs baseline: 1.1347x; 1.1347x over previous
//
#include <hip/hip_runtime.h>
#include <math.h>

// SSIM loss, fp32, N=16 C=3 H=W=512, 11x11 Gaussian sigma=1.5, zero-padded,
// separable — both blur passes on the MFMA pipe (16x16x32 bf16).
// R7: R6 structure with the spill fixed and barriers halved:
//   - launch_bounds(320,4): VGPR cap 128 (R6's (320,8) capped at 64 and
//     spilled the prefetch double-buffer -> 24 MB scratch writes).
//   - vb double-buffered in LDS -> ONE lgkm-only barrier per tile; the
//     next tile's global loads stay in flight across pass H.
// 5 waves/block, one wave per 16-col V-chunk; NT=4 row-tiles per block.

#define IMG 512
#define TW 64
#define TH 16
#define NT 4                    // vertical tiles per block
#define GXD 8
#define GYD 8                   // 512 / (TH*NT)
#define GZD 48
#define NB (GXD * GYD * GZD)    // 3072
#define VBS 88                  // vb row stride in bf16 (16B-aligned)
#define C1c 0.0001f
#define C2c 0.0009f
#define NTOTAL 12582912.0f

typedef short bf16x8 __attribute__((ext_vector_type(8)));
typedef float f32x4 __attribute__((ext_vector_type(4)));

struct GaussB { unsigned short gb[11]; };   // bf16 weights (host-RNE)

// pack bf16(a) low 16, bf16(b) high 16 — one v_perm_b32 (truncation)
__device__ __forceinline__ unsigned int pkbf(float a, float b) {
    return __builtin_amdgcn_perm(__float_as_uint(b), __float_as_uint(a),
                                 0x07060302u);
}

// wait lgkmcnt(0) ONLY (vmcnt stays outstanding), then barrier
__device__ __forceinline__ void barrier_lds_only() {
    __builtin_amdgcn_s_waitcnt(0xc07f);
    __builtin_amdgcn_s_barrier();
}

// load 8 vertically-strided pixels of column gx starting at row gy0
__device__ __forceinline__ void load_col8(const float* __restrict__ pbase,
                                          const float* __restrict__ tbase,
                                          int gx, int gy0, bool xin,
                                          float* pv, float* tv)
{
    const bool ok = xin & (gy0 >= 0) & (gy0 <= IMG - 8);
    if (ok) {
        const float* pp = pbase + gy0 * IMG + gx;
        const float* tp = tbase + gy0 * IMG + gx;
        #pragma unroll
        for (int j = 0; j < 8; ++j) {
            pv[j] = pp[j * IMG];
            tv[j] = tp[j * IMG];
        }
    } else {
        #pragma unroll
        for (int j = 0; j < 8; ++j) {
            int gy = gy0 + j;
            bool in = xin && ((unsigned)gy < (unsigned)IMG);
            int idx = in ? (gy * IMG + gx) : 0;
            float a = pbase[idx];
            float b = tbase[idx];
            pv[j] = in ? a : 0.0f;
            tv[j] = in ? b : 0.0f;
        }
    }
}

template <bool USE_ATOMIC>
__global__ __launch_bounds__(320, 4) void ssim_main(
    const float* __restrict__ pred,
    const float* __restrict__ target,
    float* __restrict__ sink,
    GaussB gwb)
{
    __shared__ unsigned short Wmat[16][32];          // 1 KB
    __shared__ unsigned short vb[2][5][16][VBS];     // 2 x 14080 B
    __shared__ float red[5];

    const int tid  = threadIdx.x;
    const int w    = tid >> 6;        // wave 0..4 (= V-chunk id)
    const int lane = tid & 63;
    const int quad = lane >> 4;
    const int n16  = lane & 15;
    const int tx0  = blockIdx.x * TW;
    const int tyb  = blockIdx.y * (TH * NT);
    const float* __restrict__ pbase = pred   + (size_t)blockIdx.z * (IMG * IMG);
    const float* __restrict__ tbase = target + (size_t)blockIdx.z * (IMG * IMG);

    // ---- W: W[i][k] = g[k-i] for k-i in [0,10], else 0 ----
    for (int idx = tid; idx < 512; idx += 320) {
        int i = idx >> 5, k = idx & 31, d = k - i;
        Wmat[i][k] = (d >= 0 && d <= 10) ? gwb.gb[d] : 0;
    }
    __syncthreads();
    const bf16x8 wfrag = *(const bf16x8*)&Wmat[n16][quad * 8];

    const int gx  = tx0 - 5 + 16 * w + n16;   // this lane's input column
    const bool xin = (unsigned)gx < (unsigned)IMG;
    const int k0  = quad * 8;                 // lane's row offset in 32-window
    const int vcol = 16 * w + 4 * quad;
    const f32x4 z = {0.0f, 0.0f, 0.0f, 0.0f};

    float pv[2][8], tv[2][8];
    load_col8(pbase, tbase, gx, tyb - 5 + k0, xin, pv[0], tv[0]);

    float lsum = 0.0f;

    #pragma unroll
    for (int i = 0; i < NT; ++i) {
        const int cur = i & 1, nxt = cur ^ 1;
        // prefetch next tile's inputs (stays in flight across pass H)
        if (i + 1 < NT)
            load_col8(pbase, tbase, gx, tyb + TH * (i + 1) - 5 + k0, xin,
                      pv[nxt], tv[nxt]);

        // ---- Pass V: products -> bf16 frag -> MFMA -> vb[cur] ----
        float ps[8], ts[8];
        #pragma unroll
        for (int j = 0; j < 8; ++j) {
            ps[j] = fmaf(pv[cur][j], 0.5f, 0.5f);
            ts[j] = fmaf(tv[cur][j], 0.5f, 0.5f);
        }
        #pragma unroll
        for (int ch = 0; ch < 5; ++ch) {
            union { bf16x8 v; unsigned int u[4]; } f;
            #pragma unroll
            for (int h = 0; h < 4; ++h) {
                float a0, a1;
                if      (ch == 0) { a0 = ps[2*h];            a1 = ps[2*h+1]; }
                else if (ch == 1) { a0 = ts[2*h];            a1 = ts[2*h+1]; }
                else if (ch == 2) { a0 = ps[2*h]*ps[2*h];    a1 = ps[2*h+1]*ps[2*h+1]; }
                else if (ch == 3) { a0 = ts[2*h]*ts[2*h];    a1 = ts[2*h+1]*ts[2*h+1]; }
                else              { a0 = ps[2*h]*ts[2*h];    a1 = ps[2*h+1]*ts[2*h+1]; }
                f.u[h] = pkbf(a0, a1);
            }
            f32x4 d = __builtin_amdgcn_mfma_f32_16x16x32_bf16(f.v, wfrag, z, 0, 0, 0);
            union { ushort4 s; unsigned int u[2]; } pk;
            pk.u[0] = pkbf(d[0], d[1]);
            pk.u[1] = pkbf(d[2], d[3]);
            *(ushort4*)&vb[cur][ch][n16][vcol] = pk.s;
        }
        // V writes of vb[cur] visible to all waves; prefetch vmcnt untouched.
        // Safe vs. reuse: Vw(i+2, cur) is separated from Hr(i, cur) by the
        // barrier of iteration i+1.
        barrier_lds_only();

        // ---- Pass H: waves 0..3 -> output cols 16w..16w+15 ----
        if (w < 4) {
            f32x4 r[5];
            #pragma unroll
            for (int ch = 0; ch < 5; ++ch) {
                bf16x8 a = *(const bf16x8*)&vb[cur][ch][n16][16 * w + 8 * quad];
                r[ch] = __builtin_amdgcn_mfma_f32_16x16x32_bf16(a, wfrag, z, 0, 0, 0);
            }
            #pragma unroll
            for (int j = 0; j < 4; ++j) {
                float mp = r[0][j], mt = r[1][j];
                float mp2 = mp * mp, mt2 = mt * mt, mpt = mp * mt;
                float sig_p  = r[2][j] - mp2;
                float sig_t  = r[3][j] - mt2;
                float sig_pt = r[4][j] - mpt;
                float num = (2.0f * mpt + C1c) * (2.0f * sig_pt + C2c);
                float den = (mp2 + mt2 + C1c) * (sig_p + sig_t + C2c);
                lsum = fmaf(num, __builtin_amdgcn_rcpf(den), lsum);
            }
        }
    }

    // ---- block reduction ----
    #pragma unroll
    for (int off = 32; off > 0; off >>= 1)
        lsum += __shfl_down(lsum, off, 64);
    if (lane == 0) red[w] = lsum;
    __syncthreads();
    if (tid == 0) {
        float s = red[0] + red[1] + red[2] + red[3];   // wave 4 contributes 0
        if (USE_ATOMIC) {
            atomicAdd(sink, s);
        } else {
            int bid = blockIdx.x + GXD * (blockIdx.y + GYD * blockIdx.z);
            sink[bid] = s;
        }
    }
}

__global__ __launch_bounds__(256) void ssim_reduce(const float* __restrict__ partials,
                                                   float* __restrict__ out)
{
    __shared__ float red[4];
    const int tid = threadIdx.x;
    float s = 0.0f;
    const float4* p4 = (const float4*)partials;
    #pragma unroll
    for (int j = 0; j < NB / 1024; ++j) {   // 3072/4 = 768 float4 / 256
        float4 v = p4[tid + 256 * j];
        s += v.x + v.y + v.z + v.w;
    }
    #pragma unroll
    for (int off = 32; off > 0; off >>= 1)
        s += __shfl_down(s, off, 64);
    if ((tid & 63) == 0) red[tid >> 6] = s;
    __syncthreads();
    if (tid == 0)
        out[0] = 1.0f - (red[0] + red[1] + red[2] + red[3]) / NTOTAL;
}

__global__ void ssim_zero(float* accum) { accum[0] = 0.0f; }
__global__ void ssim_final(const float* accum, float* out) {
    out[0] = 1.0f - accum[0] / NTOTAL;
}

extern "C" void kernel_launch(void* const* d_in, const int* in_sizes, int n_in,
                              void* d_out, int out_size, void* d_ws, size_t ws_size,
                              hipStream_t stream) {
    const float* pred   = (const float*)d_in[0];
    const float* target = (const float*)d_in[1];
    float* out = (float*)d_out;

    // Gaussian weights in double, RNE-rounded to bf16 on host
    GaussB gwb;
    double vals[11], s = 0.0;
    for (int i = 0; i < 11; ++i) {
        double d = (double)i - 5.0;
        vals[i] = exp(-(d * d) / (2.0 * 1.5 * 1.5));
        s += vals[i];
    }
    for (int i = 0; i < 11; ++i) {
        float f = (float)(vals[i] / s);
        unsigned int u;
        __builtin_memcpy(&u, &f, 4);
        unsigned int rounded = (u + 0x7FFFu + ((u >> 16) & 1u)) >> 16;  // RNE
        gwb.gb[i] = (unsigned short)rounded;
    }

    dim3 grid(GXD, GYD, GZD);   // 8 x 8 x 48 = 3072 blocks
    if (ws_size >= (size_t)NB * sizeof(float)) {
        float* partials = (float*)d_ws;
        ssim_main<false><<<grid, 320, 0, stream>>>(pred, target, partials, gwb);
        ssim_reduce<<<1, 256, 0, stream>>>(partials, out);
    } else {
        float* accum = (float*)d_ws;
        ssim_zero<<<1, 1, 0, stream>>>(accum);
        ssim_main<true><<<grid, 320, 0, stream>>>(pred, target, accum, gwb);
        ssim_final<<<1, 1, 0, stream>>>(accum, out);
    }
}

// Round 8
// 137.275 us; speedup vs baseline: 1.1632x; 1.0251x over previous
//
#include <hip/hip_runtime.h>
#include <math.h>

// SSIM loss, fp32, N=16 C=3 H=W=512, 11x11 Gaussian sigma=1.5, zero-padded,
// separable — both blur passes on the MFMA pipe (16x16x32 bf16).
// R8 = R5 skeleton (single 16x64 tile per block — best measured) +
//   (a) 5 waves/block, one wave per 16-col V-chunk (kills R5's convoy where
//       wave 0 processed 2 chunks while waves 1-3 idled at the barrier);
//   (b) packed-fp32 math (float2 ext-vectors -> v_pk_fma_f32/v_pk_mul_f32)
//       for scale, products, epilogue: ~100 fewer VALU instr/thread.
// LDS 15.4 KB; launch_bounds(320,6) caps VGPR at 85 (no spill; R6 lesson:
// watch WRITE_SIZE).

#define IMG 512
#define TW 64
#define TH 16
#define GXD 8
#define GYD 32
#define GZD 48
#define NB (GXD * GYD * GZD)    // 12288
#define VBS 88                  // vb row stride in bf16 (16B-aligned)
#define C1c 0.0001f
#define C2c 0.0009f
#define NTOTAL 12582912.0f

typedef short bf16x8 __attribute__((ext_vector_type(8)));
typedef float f32x4 __attribute__((ext_vector_type(4)));
typedef float f32x2 __attribute__((ext_vector_type(2)));

struct GaussB { unsigned short gb[11]; };   // bf16 weights (host-RNE)

// pack bf16(a) low 16, bf16(b) high 16 — one v_perm_b32 (truncation)
__device__ __forceinline__ unsigned int pkbf(float a, float b) {
    return __builtin_amdgcn_perm(__float_as_uint(b), __float_as_uint(a),
                                 0x07060302u);
}

template <bool USE_ATOMIC>
__global__ __launch_bounds__(320, 6) void ssim_main(
    const float* __restrict__ pred,
    const float* __restrict__ target,
    float* __restrict__ sink,
    GaussB gwb)
{
    __shared__ unsigned short Wmat[16][32];       // 1 KB
    __shared__ unsigned short vb[5][16][VBS];     // 14080 B
    __shared__ float red[5];

    const int tid  = threadIdx.x;
    const int w    = tid >> 6;        // wave 0..4 = V-chunk id
    const int lane = tid & 63;
    const int quad = lane >> 4;
    const int n16  = lane & 15;
    const int tx0  = blockIdx.x * TW;
    const int ty0  = blockIdx.y * TH;
    const float* __restrict__ pbase = pred   + (size_t)blockIdx.z * (IMG * IMG);
    const float* __restrict__ tbase = target + (size_t)blockIdx.z * (IMG * IMG);

    // ---- W: W[i][k] = g[k-i] for k-i in [0,10], else 0 ----
    for (int idx = tid; idx < 512; idx += 320) {
        int i = idx >> 5, k = idx & 31, d = k - i;
        Wmat[i][k] = (d >= 0 && d <= 10) ? gwb.gb[d] : 0;
    }
    __syncthreads();
    const bf16x8 wfrag = *(const bf16x8*)&Wmat[n16][quad * 8];

    const int gx   = tx0 - 5 + 16 * w + n16;   // this lane's input column
    const bool xin = (unsigned)gx < (unsigned)IMG;
    const int k0   = quad * 8;                 // lane's row offset in 32-window
    const int gy0  = ty0 - 5 + k0;             // first of 8 input rows
    const int vcol = 16 * w + 4 * quad;
    const f32x4 z = {0.0f, 0.0f, 0.0f, 0.0f};

    // ---- loads: 8 vertically-strided pixels of column gx, p and t ----
    float pv[8], tv[8];
    {
        const bool ok = xin & (gy0 >= 0) & (gy0 <= IMG - 8);
        if (ok) {
            const float* pp = pbase + gy0 * IMG + gx;
            const float* tp = tbase + gy0 * IMG + gx;
            #pragma unroll
            for (int j = 0; j < 8; ++j) {
                pv[j] = pp[j * IMG];
                tv[j] = tp[j * IMG];
            }
        } else {
            #pragma unroll
            for (int j = 0; j < 8; ++j) {
                int gy = gy0 + j;
                bool in = xin && ((unsigned)gy < (unsigned)IMG);
                int idx = in ? (gy * IMG + gx) : 0;
                float a = pbase[idx];
                float b = tbase[idx];
                pv[j] = in ? a : 0.0f;
                tv[j] = in ? b : 0.0f;
            }
        }
    }

    // ---- Pass V: scale+products in packed fp32, pack bf16, MFMA, vb ----
    const f32x2 halfv = {0.5f, 0.5f};
    f32x2 p2[4], t2[4];
    #pragma unroll
    for (int h = 0; h < 4; ++h) {
        f32x2 pr = {pv[2*h], pv[2*h+1]};
        f32x2 tr = {tv[2*h], tv[2*h+1]};
        p2[h] = pr * halfv + halfv;     // v_pk_fma_f32
        t2[h] = tr * halfv + halfv;
    }
    #pragma unroll
    for (int ch = 0; ch < 5; ++ch) {
        union { bf16x8 v; unsigned int u[4]; } f;
        #pragma unroll
        for (int h = 0; h < 4; ++h) {
            f32x2 q;
            if      (ch == 0) q = p2[h];
            else if (ch == 1) q = t2[h];
            else if (ch == 2) q = p2[h] * p2[h];   // v_pk_mul_f32
            else if (ch == 3) q = t2[h] * t2[h];
            else              q = p2[h] * t2[h];
            f.u[h] = pkbf(q.x, q.y);
        }
        f32x4 d = __builtin_amdgcn_mfma_f32_16x16x32_bf16(f.v, wfrag, z, 0, 0, 0);
        union { ushort4 s; unsigned int u[2]; } pk;
        pk.u[0] = pkbf(d[0], d[1]);
        pk.u[1] = pkbf(d[2], d[3]);
        *(ushort4*)&vb[ch][n16][vcol] = pk.s;
    }
    __syncthreads();

    // ---- Pass H: waves 0..3 -> output cols 16w..16w+15 ----
    float lsum = 0.0f;
    if (w < 4) {
        f32x4 r[5];
        #pragma unroll
        for (int ch = 0; ch < 5; ++ch) {
            bf16x8 a = *(const bf16x8*)&vb[ch][n16][16 * w + 8 * quad];
            r[ch] = __builtin_amdgcn_mfma_f32_16x16x32_bf16(a, wfrag, z, 0, 0, 0);
        }
        const f32x2 twov = {2.0f, 2.0f};
        const f32x2 c1v  = {C1c, C1c};
        const f32x2 c2v  = {C2c, C2c};
        #pragma unroll
        for (int jj = 0; jj < 2; ++jj) {
            f32x2 mp  = {r[0][2*jj], r[0][2*jj+1]};
            f32x2 mt  = {r[1][2*jj], r[1][2*jj+1]};
            f32x2 epp = {r[2][2*jj], r[2][2*jj+1]};
            f32x2 ett = {r[3][2*jj], r[3][2*jj+1]};
            f32x2 ept = {r[4][2*jj], r[4][2*jj+1]};
            f32x2 mp2 = mp * mp;
            f32x2 mt2 = mt * mt;
            f32x2 mpt = mp * mt;
            f32x2 sp_ = epp - mp2;
            f32x2 st_ = ett - mt2;
            f32x2 spt = ept - mpt;
            f32x2 num = (mpt * twov + c1v) * (spt * twov + c2v);
            f32x2 den = (mp2 + mt2 + c1v) * (sp_ + st_ + c2v);
            lsum = fmaf(num.x, __builtin_amdgcn_rcpf(den.x), lsum);
            lsum = fmaf(num.y, __builtin_amdgcn_rcpf(den.y), lsum);
        }
    }

    // ---- block reduction ----
    #pragma unroll
    for (int off = 32; off > 0; off >>= 1)
        lsum += __shfl_down(lsum, off, 64);
    if (lane == 0) red[w] = lsum;
    __syncthreads();
    if (tid == 0) {
        float s = red[0] + red[1] + red[2] + red[3];   // wave 4 contributes 0
        if (USE_ATOMIC) {
            atomicAdd(sink, s);
        } else {
            int bid = blockIdx.x + GXD * (blockIdx.y + GYD * blockIdx.z);
            sink[bid] = s;
        }
    }
}

__global__ __launch_bounds__(256) void ssim_reduce(const float* __restrict__ partials,
                                                   float* __restrict__ out)
{
    __shared__ float red[4];
    const int tid = threadIdx.x;
    float s = 0.0f;
    const float4* p4 = (const float4*)partials;
    #pragma unroll
    for (int j = 0; j < NB / 1024; ++j) {   // 12288/4 = 3072 float4 / 256
        float4 v = p4[tid + 256 * j];
        s += v.x + v.y + v.z + v.w;
    }
    #pragma unroll
    for (int off = 32; off > 0; off >>= 1)
        s += __shfl_down(s, off, 64);
    if ((tid & 63) == 0) red[tid >> 6] = s;
    __syncthreads();
    if (tid == 0)
        out[0] = 1.0f - (red[0] + red[1] + red[2] + red[3]) / NTOTAL;
}

__global__ void ssim_zero(float* accum) { accum[0] = 0.0f; }
__global__ void ssim_final(const float* accum, float* out) {
    out[0] = 1.0f - accum[0] / NTOTAL;
}

extern "C" void kernel_launch(void* const* d_in, const int* in_sizes, int n_in,
                              void* d_out, int out_size, void* d_ws, size_t ws_size,
                              hipStream_t stream) {
    const float* pred   = (const float*)d_in[0];
    const float* target = (const float*)d_in[1];
    float* out = (float*)d_out;

    // Gaussian weights in double, RNE-rounded to bf16 on host
    GaussB gwb;
    double vals[11], s = 0.0;
    for (int i = 0; i < 11; ++i) {
        double d = (double)i - 5.0;
        vals[i] = exp(-(d * d) / (2.0 * 1.5 * 1.5));
        s += vals[i];
    }
    for (int i = 0; i < 11; ++i) {
        float f = (float)(vals[i] / s);
        unsigned int u;
        __builtin_memcpy(&u, &f, 4);
        unsigned int rounded = (u + 0x7FFFu + ((u >> 16) & 1u)) >> 16;  // RNE
        gwb.gb[i] = (unsigned short)rounded;
    }

    dim3 grid(GXD, GYD, GZD);   // 8 x 32 x 48 = 12288 blocks
    if (ws_size >= (size_t)NB * sizeof(float)) {
        float* partials = (float*)d_ws;
        ssim_main<false><<<grid, 320, 0, stream>>>(pred, target, partials, gwb);
        ssim_reduce<<<1, 256, 0, stream>>>(partials, out);
    } else {
        float* accum = (float*)d_ws;
        ssim_zero<<<1, 1, 0, stream>>>(accum);
        ssim_main<true><<<grid, 320, 0, stream>>>(pred, target, accum, gwb);
        ssim_final<<<1, 1, 0, stream>>>(accum, out);
    }
}